// Round 1
// baseline (1057.561 us; speedup 1.0000x reference)
//
#include <hip/hip_runtime.h>

#define N_NODES 1000000
#define D       128
#define T_STEPS 100
#define B       1024
#define K       6
#define ALPHA   0.025f

__device__ __forceinline__ float wave_reduce_sum(float v) {
#pragma unroll
    for (int off = 32; off > 0; off >>= 1)
        v += __shfl_xor(v, off, 64);
    return v;
}

// One wave (64 lanes) per edge: gather u-row + 6 target rows (pre-update values),
// compute g = alpha*(label - sigmoid(u.v)), accumulate vec_error in registers,
// write err[b*D + d] to workspace. No writes to emb here -> all reads in this
// kernel see the state at the start of the step.
__global__ __launch_bounds__(256) void line_grad(const float* __restrict__ emb,
                                                 const int*   __restrict__ u_idx,   // [B]
                                                 const int*   __restrict__ tgt_idx, // [B*K]
                                                 float*       __restrict__ err)     // [B*D]
{
    const int wave = (blockIdx.x * blockDim.x + threadIdx.x) >> 6; // edge index b
    const int lane = threadIdx.x & 63;
    if (wave >= B) return;
    const int b = wave;

    const int u = u_idx[b];
    const float2 u2 = ((const float2*)(emb + (size_t)u * D))[lane];

    float2 e2 = make_float2(0.0f, 0.0f);
#pragma unroll
    for (int k = 0; k < K; ++k) {
        const int v = tgt_idx[b * K + k];
        const float2 v2 = ((const float2*)(emb + (size_t)v * D))[lane];
        const float part = u2.x * v2.x + u2.y * v2.y;
        const float s = wave_reduce_sum(part);
        const float f = 1.0f / (1.0f + expf(-s));
        const float label = (k == 0) ? 1.0f : 0.0f;
        const float g = ALPHA * (label - f);
        e2.x += g * v2.x;
        e2.y += g * v2.y;
    }
    ((float2*)(err + (size_t)b * D))[lane] = e2;
}

// Scatter: emb[u[b]] += err[b]. atomicAdd handles duplicate u within the batch
// (matches jnp .at[u].add accumulation semantics).
__global__ __launch_bounds__(256) void line_apply(float*       __restrict__ emb,
                                                  const int*   __restrict__ u_idx, // [B]
                                                  const float* __restrict__ err)   // [B*D]
{
    const int tid = blockIdx.x * blockDim.x + threadIdx.x; // B*D threads
    const int b = tid >> 7;       // D == 128
    const int d = tid & (D - 1);
    const int u = u_idx[b];
    atomicAdd(emb + (size_t)u * D + d, err[tid]);
}

// Final L2 row-normalization, in place. One wave per row, float2 per lane.
__global__ __launch_bounds__(256) void normalize_rows(float* __restrict__ out)
{
    const size_t row = (size_t)blockIdx.x * 4 + (threadIdx.x >> 6);
    const int lane = threadIdx.x & 63;
    float2* p = (float2*)(out + row * D);
    float2 v = p[lane];
    float ss = v.x * v.x + v.y * v.y;
    ss = wave_reduce_sum(ss);
    const float norm = sqrtf(ss);
    const float inv = 1.0f / fmaxf(norm, 1e-12f);
    v.x *= inv;
    v.y *= inv;
    p[lane] = v;
}

extern "C" void kernel_launch(void* const* d_in, const int* in_sizes, int n_in,
                              void* d_out, int out_size, void* d_ws, size_t ws_size,
                              hipStream_t stream)
{
    const float* emb_in  = (const float*)d_in[0]; // [N, D] f32
    const int*   u_idx   = (const int*)d_in[1];   // [T, B] i32
    const int*   tgt_idx = (const int*)d_in[2];   // [T, B, K] i32
    float*       out     = (float*)d_out;         // [N, D] f32
    float*       err     = (float*)d_ws;          // B*D floats = 512 KB scratch

    // Working copy: SGD runs in-place on d_out so inputs stay pristine and the
    // buffer is re-initialized deterministically on every call.
    hipMemcpyAsync(out, emb_in, (size_t)N_NODES * D * sizeof(float),
                   hipMemcpyDeviceToDevice, stream);

    for (int t = 0; t < T_STEPS; ++t) {
        // Kernel boundary between grad and apply = grid-wide barrier:
        // all gathers of step t read pre-update rows (matches reference scan).
        line_grad<<<B / 4, 256, 0, stream>>>(out,
                                             u_idx + (size_t)t * B,
                                             tgt_idx + (size_t)t * B * K,
                                             err);
        line_apply<<<(B * D) / 256, 256, 0, stream>>>(out,
                                                      u_idx + (size_t)t * B,
                                                      err);
    }

    normalize_rows<<<N_NODES / 4, 256, 0, stream>>>(out);
}